// Round 5
// baseline (595.225 us; speedup 1.0000x reference)
//
#include <hip/hip_runtime.h>

// GCN_84499186582104 — fully fused, one thread per (batch, node).
// B=131072, V=8, NFEAT=32, NHID1=16, NHID12=8, NCLASS=2.
// R5: persistent waves + register-prefetch software pipeline.
//   - 2048 blocks (whole grid co-resident, 16 waves/CU), grid-stride over
//     8192 groups: each wave does 4 iterations.
//   - x row (type + 8 float4, 33 VGPRs) prefetched one iteration ahead:
//     its vmcnt-wait lands at next iteration's copy -> ~3000 cycles of
//     compute cover the HBM latency. adj/edge issued ~400 cyc before use.
//   - Zero __syncthreads (slot = 8 lanes of one wave; DS pipe in-order
//     per wave; wave_barrier = 0-inst code-motion fence).
//   - Pooling via per-thread gate-row Y + one 8x8 LDS transpose
//     (5 writes + 24 reads vs 9 + 72 in R4).

#define SLOTS 16      // batches per block
#define NTHREADS 128  // 8 threads per batch; slots never span a wave
#define NBLOCKS 2048  // 8 blocks/CU -> fully resident grid

typedef float4 __attribute__((aligned(4))) f4u;   // dword-aligned float4 load

__device__ __forceinline__ float grp_sum8(float x) {
    x += __shfl_xor(x, 1);
    x += __shfl_xor(x, 2);
    x += __shfl_xor(x, 4);
    return x;
}
__device__ __forceinline__ void wavefence() { __builtin_amdgcn_wave_barrier(); }

__global__ __launch_bounds__(NTHREADS, 4)
void gcn_fused(const float* __restrict__ x,
               const float* __restrict__ adj,
               const float* __restrict__ edge,
               const float* __restrict__ wb, const float* __restrict__ bb,
               const float* __restrict__ w1, const float* __restrict__ b1,
               const float* __restrict__ w2, const float* __restrict__ b2,
               const float* __restrict__ wg, const float* __restrict__ bg,
               const float* __restrict__ wf, const float* __restrict__ bf,
               float* __restrict__ out, int nGroups)
{
    // bufA roles (slot-private, serialized by per-wave DS order):
    //   Fk[o*8+v] -> S[o*8+v] -> g2[v*8+n] -> h2[v*8+n]
    // bufB roles: g1[v*16+j] (dead after msg1) -> Y[v*8+o] @0 + type[v] @64
    __shared__ float bufA[SLOTS * 72];   //  4608 B
    __shared__ float bufB[SLOTS * 136];  //  8704 B  -> 13312 B/block

    const int tid  = threadIdx.x;
    const int slot = tid >> 3;
    const int v    = tid & 7;
    float* A  = &bufA[slot * 72];
    float* Bg = &bufB[slot * 136];

    const int stride = gridDim.x;

    // ---- prologue: prefetch group blockIdx.x's x row ----
    float ntype; float4 nq[8];
    {
        const size_t nb = (size_t)blockIdx.x * SLOTS + slot;
        const float* xr = x + nb * 264 + (size_t)v * 33;
        ntype = xr[0];
        const f4u* xq = (const f4u*)(xr + 1);
#pragma unroll
        for (int k = 0; k < 8; ++k) nq[k] = xq[k];
    }

    for (int g = blockIdx.x; g < nGroups; g += stride) {
        const size_t b = (size_t)g * SLOTS + slot;

        // ---- consume prefetch (vmcnt wait lands here), re-issue for g+stride
        const float type = ntype;
        float4 q[8];
#pragma unroll
        for (int k = 0; k < 8; ++k) q[k] = nq[k];
        {
            int ng = g + stride; if (ng >= nGroups) ng = g;  // benign reload
            const size_t nb = (size_t)ng * SLOTS + slot;
            const float* xr = x + nb * 264 + (size_t)v * 33;
            ntype = xr[0];
            const f4u* xq = (const f4u*)(xr + 1);
#pragma unroll
            for (int k = 0; k < 8; ++k) nq[k] = xq[k];
        }

        wavefence();   // prior iteration's pool reads precede this iter's writes

        // ---- Fk column + g1 row, fused accumulation over features ----
        float Fk[8];
#pragma unroll
        for (int o = 0; o < 8; ++o) Fk[o] = bb[o];
        float g1[16];
#pragma unroll
        for (int j = 0; j < 16; ++j) g1[j] = 0.f;
#pragma unroll
        for (int k = 0; k < 8; ++k) {
            const float f[4] = { q[k].x, q[k].y, q[k].z, q[k].w };
#pragma unroll
            for (int u = 0; u < 4; ++u) {
                const int c = 4 * k + u;
                const float fv = f[u];
#pragma unroll
                for (int o = 0; o < 8; ++o) Fk[o] += fv * wb[o * 32 + c];
#pragma unroll
                for (int j = 0; j < 16; ++j) g1[j] += fv * w1[c * 16 + j];
            }
        }

        // ---- adj/edge issued here: ~400+ cycles before use at W ----
        const float4* ar = (const float4*)(adj  + b * 64 + (size_t)v * 8);
        const float4* er = (const float4*)(edge + b * 64 + (size_t)v * 8);
        const float4 a0 = ar[0], a1 = ar[1];
        const float4 e0 = er[0], e1 = er[1];

        // ---- share Fk (column v) and g1 (row v) — intra-wave only ----
#pragma unroll
        for (int o = 0; o < 8; ++o) A[o * 8 + v] = Fk[o];
        {
            float4* gp = (float4*)(Bg + v * 16);
            gp[0] = make_float4(g1[0],  g1[1],  g1[2],  g1[3]);
            gp[1] = make_float4(g1[4],  g1[5],  g1[6],  g1[7]);
            gp[2] = make_float4(g1[8],  g1[9],  g1[10], g1[11]);
            gp[3] = make_float4(g1[12], g1[13], g1[14], g1[15]);
        }
        wavefence();

        // ---- M[o][v] = sum_k Fk[o][k]*Fk[k][v]; softmax over o ----
        float M[8];
#pragma unroll
        for (int o = 0; o < 8; ++o) {
            const float4* fr = (const float4*)(A + o * 8);
            const float4 r0 = fr[0], r1 = fr[1];
            M[o] = r0.x * Fk[0] + r0.y * Fk[1] + r0.z * Fk[2] + r0.w * Fk[3]
                 + r1.x * Fk[4] + r1.y * Fk[5] + r1.z * Fk[6] + r1.w * Fk[7];
        }
        wavefence();
        float mx = M[0];
#pragma unroll
        for (int o = 1; o < 8; ++o) mx = fmaxf(mx, M[o]);
        float ssum = 0.f;
#pragma unroll
        for (int o = 0; o < 8; ++o) { M[o] = __expf(M[o] - mx); ssum += M[o]; }
        const float sinv = 1.f / ssum;
#pragma unroll
        for (int o = 0; o < 8; ++o) A[o * 8 + v] = M[o] * sinv;   // S column
        wavefence();

        // ---- W row: W[v][w] = adj * (S + edge) ----
        const float4* sr = (const float4*)(A + v * 8);
        const float4 s0 = sr[0], s1 = sr[1];
        float W[8];
        W[0] = a0.x * (s0.x + e0.x);  W[1] = a0.y * (s0.y + e0.y);
        W[2] = a0.z * (s0.z + e0.z);  W[3] = a0.w * (s0.w + e0.w);
        W[4] = a1.x * (s1.x + e1.x);  W[5] = a1.y * (s1.y + e1.y);
        W[6] = a1.z * (s1.z + e1.z);  W[7] = a1.w * (s1.w + e1.w);

        // ---- layer 1: h = leaky(W @ g1 + b1) ----
        float msg1[16];
#pragma unroll
        for (int j = 0; j < 16; ++j) msg1[j] = 0.f;
#pragma unroll
        for (int w = 0; w < 8; ++w) {
            const float wv = W[w];
            const float4* gp = (const float4*)(Bg + w * 16);
            const float4 q0 = gp[0], q1 = gp[1], q2 = gp[2], q3 = gp[3];
            msg1[0]  += wv * q0.x; msg1[1]  += wv * q0.y; msg1[2]  += wv * q0.z; msg1[3]  += wv * q0.w;
            msg1[4]  += wv * q1.x; msg1[5]  += wv * q1.y; msg1[6]  += wv * q1.z; msg1[7]  += wv * q1.w;
            msg1[8]  += wv * q2.x; msg1[9]  += wv * q2.y; msg1[10] += wv * q2.z; msg1[11] += wv * q2.w;
            msg1[12] += wv * q3.x; msg1[13] += wv * q3.y; msg1[14] += wv * q3.z; msg1[15] += wv * q3.w;
        }
        float h[16];
#pragma unroll
        for (int j = 0; j < 16; ++j) {
            const float t = msg1[j] + b1[j];
            h[j] = t > 0.f ? t : 0.01f * t;
        }

        // ---- g2 row: g2[v][n] = dot(h_v, w2[:,n]) ----
        float g2[8];
#pragma unroll
        for (int n = 0; n < 8; ++n) g2[n] = 0.f;
#pragma unroll
        for (int j = 0; j < 16; ++j) {
            const float hv = h[j];
#pragma unroll
            for (int n = 0; n < 8; ++n) g2[n] += hv * w2[j * 8 + n];
        }
        wavefence();   // S reads done -> overwrite A with g2
        {
            float4* gp = (float4*)(A + v * 8);
            gp[0] = make_float4(g2[0], g2[1], g2[2], g2[3]);
            gp[1] = make_float4(g2[4], g2[5], g2[6], g2[7]);
        }
        wavefence();

        // ---- layer 2: h2 = leaky(W @ g2 + b2) ----
        float msg2[8];
#pragma unroll
        for (int n = 0; n < 8; ++n) msg2[n] = 0.f;
#pragma unroll
        for (int w = 0; w < 8; ++w) {
            const float wv = W[w];
            const float4* gp = (const float4*)(A + w * 8);
            const float4 q0 = gp[0], q1 = gp[1];
            msg2[0] += wv * q0.x; msg2[1] += wv * q0.y; msg2[2] += wv * q0.z; msg2[3] += wv * q0.w;
            msg2[4] += wv * q1.x; msg2[5] += wv * q1.y; msg2[6] += wv * q1.z; msg2[7] += wv * q1.w;
        }
        float h2[8];
#pragma unroll
        for (int n = 0; n < 8; ++n) {
            const float t = msg2[n] + b2[n];
            h2[n] = t > 0.f ? t : 0.01f * t;
        }

        // ---- gate-logit row: Y[o] = dot(h2_v, wg[o,:]) (no LDS) ----
        float Y[8];
#pragma unroll
        for (int o = 0; o < 8; ++o) {
            float acc = 0.f;
#pragma unroll
            for (int n = 0; n < 8; ++n) acc += h2[n] * wg[o * 8 + n];
            Y[o] = acc;
        }
        wavefence();   // g2 reads done -> overwrite A with h2; Bg(g1) dead -> Y/type
        {
            float4* hp = (float4*)(A + v * 8);
            hp[0] = make_float4(h2[0], h2[1], h2[2], h2[3]);
            hp[1] = make_float4(h2[4], h2[5], h2[6], h2[7]);
            float4* yp = (float4*)(Bg + v * 8);
            yp[0] = make_float4(Y[0], Y[1], Y[2], Y[3]);
            yp[1] = make_float4(Y[4], Y[5], Y[6], Y[7]);
            Bg[64 + v] = type;
        }
        wavefence();

        // ---- attention pooling: thread handles gate-row o = v.
        // bg[o] constant along softmax axis (v') -> drops out; masked rows logit 0.
        const int o = v;
        float yc[8], hc[8], ty[8];
#pragma unroll
        for (int vp = 0; vp < 8; ++vp) {
            yc[vp] = Bg[vp * 8 + o];
            hc[vp] = A[vp * 8 + o];
            ty[vp] = Bg[64 + vp];
        }
        float xp = 0.f;
#pragma unroll
        for (int t = 0; t < 2; ++t) {
            const float tv = (float)t;
            float l[8];
            float lmx = -1e30f;
#pragma unroll
            for (int vp = 0; vp < 8; ++vp) {
                l[vp] = (ty[vp] == tv) ? yc[vp] : 0.f;
                lmx = fmaxf(lmx, l[vp]);
            }
            float esum = 0.f, num = 0.f;
#pragma unroll
            for (int vp = 0; vp < 8; ++vp) {
                const float e = __expf(l[vp] - lmx);
                esum += e;
                num  += (ty[vp] == tv) ? e * hc[vp] : 0.f;
            }
            xp += 0.5f * num / esum;
        }

        // ---- classifier ----
        const float y0 = grp_sum8(xp * wf[0 * 8 + o]);
        const float y1 = grp_sum8(xp * wf[1 * 8 + o]);
        if (v == 0) {
            float2* op = (float2*)(out + b * 2);
            *op = make_float2(y0 + bf[0], y1 + bf[1]);
        }
    }
}

extern "C" void kernel_launch(void* const* d_in, const int* in_sizes, int n_in,
                              void* d_out, int out_size, void* d_ws, size_t ws_size,
                              hipStream_t stream) {
    const float* x    = (const float*)d_in[0];
    const float* adj  = (const float*)d_in[1];
    const float* edge = (const float*)d_in[2];
    // d_in[3]=wa, d_in[4]=ba unused by the reference.
    const float* wb   = (const float*)d_in[5];
    const float* bb   = (const float*)d_in[6];
    const float* w1   = (const float*)d_in[7];
    const float* b1   = (const float*)d_in[8];
    const float* w2   = (const float*)d_in[9];
    const float* b2   = (const float*)d_in[10];
    const float* wg   = (const float*)d_in[11];
    const float* bg   = (const float*)d_in[12];
    const float* wf   = (const float*)d_in[13];
    const float* bf   = (const float*)d_in[14];
    float* out = (float*)d_out;

    const int Btot    = in_sizes[0] / 264;            // B = 131072
    const int nGroups = (Btot + SLOTS - 1) / SLOTS;   // 8192
    const int grid    = nGroups < NBLOCKS ? nGroups : NBLOCKS;

    gcn_fused<<<grid, NTHREADS, 0, stream>>>(x, adj, edge, wb, bb, w1, b1,
                                             w2, b2, wg, bg, wf, bf, out, nGroups);
}

// Round 6
// 275.749 us; speedup vs baseline: 2.1586x; 2.1586x over previous
//
#include <hip/hip_runtime.h>

// GCN_84499186582104 — fully fused, one thread per (batch, node).
// B=131072, V=8, NFEAT=32, NHID1=16, NHID12=8, NCLASS=2.
// R6 (base = R4, best 119.6us):
//   - Weights staged to LDS once per block (wb/wg transposed). Kills the
//     per-wave s_load storms: SMEM returns out-of-order => every weight use
//     forced lgkmcnt(0) full drains. DS reads are in-order + broadcast.
//   - Packed fp32 (v_pk_fma_f32) via float2 ext-vectors in all hot loops;
//     leaky = pk_max(t, 0.01t). ~2x fewer VALU instructions.
//   - Register budget kept <= 64 (R3/R5 lesson: compiler pins 64, spills
//     above). adj/edge loads issued after the Fk/g1 loop.
//   - Zero per-phase __syncthreads (slot = 8 lanes of one wave; DS in-order
//     per wave; wave_barrier = 0-inst fence). One syncthreads after staging.

#define SLOTS 16      // batches per block
#define NTHREADS 128  // 8 threads per batch; slots never span a wave

typedef float v2f __attribute__((ext_vector_type(2)));
typedef float4 __attribute__((aligned(4))) f4u;   // dword-aligned float4 load

// LDS weight-cache offsets (floats)
#define WBT 0     // wbT[c*8+o] = wb[o*32+c]      (256)
#define W1O 256   // w1[c*16+j] natural           (512)
#define W2O 768   // w2[j*8+n]  natural           (128)
#define WGT 896   // wgT[n*8+o] = wg[o*8+n]       (64)
#define BBO 960   // bb                           (8)
#define B1O 968   // b1                           (16)
#define B2O 984   // b2                           (8)
#define NWF 992

__device__ __forceinline__ float grp_sum8(float x) {
    x += __shfl_xor(x, 1);
    x += __shfl_xor(x, 2);
    x += __shfl_xor(x, 4);
    return x;
}
__device__ __forceinline__ void wavefence() { __builtin_amdgcn_wave_barrier(); }
__device__ __forceinline__ v2f mkv(float a, float b) { v2f r; r.x = a; r.y = b; return r; }

__global__ __launch_bounds__(NTHREADS, 4)
void gcn_fused(const float* __restrict__ x,
               const float* __restrict__ adj,
               const float* __restrict__ edge,
               const float* __restrict__ wb, const float* __restrict__ bb,
               const float* __restrict__ w1, const float* __restrict__ b1,
               const float* __restrict__ w2, const float* __restrict__ b2,
               const float* __restrict__ wg, const float* __restrict__ bg,
               const float* __restrict__ wf, const float* __restrict__ bf,
               float* __restrict__ out, int nGroups)
{
    // bufA roles (slot-private, per-wave DS order): Fk[o*8+v] -> S[o*8+v]
    //   -> g2[v*8+n] -> h2[v*8+n].  bufB: g1[v*16+j] -> Y[v*8+o] + type[64+v]
    __shared__ float bufA[SLOTS * 72];   //  4608 B
    __shared__ float bufB[SLOTS * 136];  //  8704 B
    __shared__ float wS[NWF];            //  3968 B  -> 17280 B/block

    const int tid  = threadIdx.x;
    const int slot = tid >> 3;
    const int v    = tid & 7;
    float* A  = &bufA[slot * 72];
    float* Bg = &bufB[slot * 136];

    // ---- stage weights into LDS (once per block) ----
    {
        for (int i = tid; i < 256; i += NTHREADS) {        // wb transposed
            const int c = i >> 3, o = i & 7;
            wS[WBT + i] = wb[o * 32 + c];
        }
        for (int i = tid; i < 512; i += NTHREADS) wS[W1O + i] = w1[i];
        if (tid < 128) wS[W2O + tid] = w2[tid];
        if (tid < 64) {                                     // wg transposed
            const int n = tid >> 3, o = tid & 7;
            wS[WGT + tid] = wg[o * 8 + n];
        }
        if (tid < 8)  wS[BBO + tid] = bb[tid];
        if (tid < 16) wS[B1O + tid] = b1[tid];
        if (tid < 8)  wS[B2O + tid] = b2[tid];
    }
    __syncthreads();

    long long bb_ = (long long)blockIdx.x * SLOTS + slot;
    if (bb_ >= (long long)nGroups * SLOTS) bb_ = (long long)nGroups * SLOTS - 1;
    const size_t b = (size_t)bb_;

    // ---- x row: type + 32 features (8 dword-aligned float4) ----
    const float* xr = x + b * 264 + (size_t)v * 33;
    const float type = xr[0];
    const f4u* xq = (const f4u*)(xr + 1);
    float4 q[8];
#pragma unroll
    for (int k = 0; k < 8; ++k) q[k] = xq[k];

    // ---- Fk (output-paired) + g1 (output-paired), packed fp32 ----
    v2f Fk2[4];
    {
        const v2f* bbp = (const v2f*)&wS[BBO];
#pragma unroll
        for (int p = 0; p < 4; ++p) Fk2[p] = bbp[p];
    }
    v2f g12[8];
#pragma unroll
    for (int p = 0; p < 8; ++p) g12[p] = mkv(0.f, 0.f);
#pragma unroll
    for (int k = 0; k < 8; ++k) {
        const float f[4] = { q[k].x, q[k].y, q[k].z, q[k].w };
#pragma unroll
        for (int u = 0; u < 4; ++u) {
            const int c = 4 * k + u;
            const v2f f2 = mkv(f[u], f[u]);
            const float4* wbc = (const float4*)&wS[WBT + c * 8];
            const float4 wa = wbc[0], wbq = wbc[1];
            Fk2[0] = __builtin_elementwise_fma(f2, mkv(wa.x,  wa.y),  Fk2[0]);
            Fk2[1] = __builtin_elementwise_fma(f2, mkv(wa.z,  wa.w),  Fk2[1]);
            Fk2[2] = __builtin_elementwise_fma(f2, mkv(wbq.x, wbq.y), Fk2[2]);
            Fk2[3] = __builtin_elementwise_fma(f2, mkv(wbq.z, wbq.w), Fk2[3]);
            const float4* w1c = (const float4*)&wS[W1O + c * 16];
            const float4 wc0 = w1c[0], wc1 = w1c[1], wc2 = w1c[2], wc3 = w1c[3];
            g12[0] = __builtin_elementwise_fma(f2, mkv(wc0.x, wc0.y), g12[0]);
            g12[1] = __builtin_elementwise_fma(f2, mkv(wc0.z, wc0.w), g12[1]);
            g12[2] = __builtin_elementwise_fma(f2, mkv(wc1.x, wc1.y), g12[2]);
            g12[3] = __builtin_elementwise_fma(f2, mkv(wc1.z, wc1.w), g12[3]);
            g12[4] = __builtin_elementwise_fma(f2, mkv(wc2.x, wc2.y), g12[4]);
            g12[5] = __builtin_elementwise_fma(f2, mkv(wc2.z, wc2.w), g12[5]);
            g12[6] = __builtin_elementwise_fma(f2, mkv(wc3.x, wc3.y), g12[6]);
            g12[7] = __builtin_elementwise_fma(f2, mkv(wc3.z, wc3.w), g12[7]);
        }
    }

    // ---- adj/edge issued here (hundreds of cycles before use at W) ----
    const float4* ar = (const float4*)(adj  + b * 64 + (size_t)v * 8);
    const float4* er = (const float4*)(edge + b * 64 + (size_t)v * 8);
    const float4 a0 = ar[0], a1 = ar[1];
    const float4 e0 = er[0], e1 = er[1];

    // ---- share Fk (column v) and g1 (row v) ----
#pragma unroll
    for (int p = 0; p < 4; ++p) {
        A[(2 * p)     * 8 + v] = Fk2[p].x;
        A[(2 * p + 1) * 8 + v] = Fk2[p].y;
    }
    {
        float4* gp = (float4*)(Bg + v * 16);
        gp[0] = make_float4(g12[0].x, g12[0].y, g12[1].x, g12[1].y);
        gp[1] = make_float4(g12[2].x, g12[2].y, g12[3].x, g12[3].y);
        gp[2] = make_float4(g12[4].x, g12[4].y, g12[5].x, g12[5].y);
        gp[3] = make_float4(g12[6].x, g12[6].y, g12[7].x, g12[7].y);
    }
    wavefence();

    // ---- M[o][v] = dot(FkS row o, Fk column v); softmax over o ----
    float M[8];
#pragma unroll
    for (int o = 0; o < 8; ++o) {
        const float4* fr = (const float4*)(A + o * 8);
        const float4 r0 = fr[0], r1 = fr[1];
        v2f acc = mkv(0.f, 0.f);
        acc = __builtin_elementwise_fma(mkv(r0.x, r0.y), Fk2[0], acc);
        acc = __builtin_elementwise_fma(mkv(r0.z, r0.w), Fk2[1], acc);
        acc = __builtin_elementwise_fma(mkv(r1.x, r1.y), Fk2[2], acc);
        acc = __builtin_elementwise_fma(mkv(r1.z, r1.w), Fk2[3], acc);
        M[o] = acc.x + acc.y;
    }
    wavefence();
    float mx = M[0];
#pragma unroll
    for (int o = 1; o < 8; ++o) mx = fmaxf(mx, M[o]);
    float ssum = 0.f;
#pragma unroll
    for (int o = 0; o < 8; ++o) { M[o] = __expf(M[o] - mx); ssum += M[o]; }
    const float sinv = 1.f / ssum;
#pragma unroll
    for (int o = 0; o < 8; ++o) A[o * 8 + v] = M[o] * sinv;   // S column
    wavefence();

    // ---- W row (packed): W = adj * (S + edge) ----
    const float4* sr = (const float4*)(A + v * 8);
    const float4 s0 = sr[0], s1 = sr[1];
    v2f W2[4];
    W2[0] = mkv(a0.x, a0.y) * (mkv(s0.x, s0.y) + mkv(e0.x, e0.y));
    W2[1] = mkv(a0.z, a0.w) * (mkv(s0.z, s0.w) + mkv(e0.z, e0.w));
    W2[2] = mkv(a1.x, a1.y) * (mkv(s1.x, s1.y) + mkv(e1.x, e1.y));
    W2[3] = mkv(a1.z, a1.w) * (mkv(s1.z, s1.w) + mkv(e1.z, e1.w));

    // ---- layer 1: h = leaky(W @ g1 + b1), packed ----
    v2f m1[8];
#pragma unroll
    for (int p = 0; p < 8; ++p) m1[p] = mkv(0.f, 0.f);
#pragma unroll
    for (int w = 0; w < 8; ++w) {
        const float wv = (w & 1) ? W2[w >> 1].y : W2[w >> 1].x;
        const v2f f2 = mkv(wv, wv);
        const float4* gp = (const float4*)(Bg + w * 16);
        const float4 q0 = gp[0], q1 = gp[1], q2 = gp[2], q3 = gp[3];
        m1[0] = __builtin_elementwise_fma(f2, mkv(q0.x, q0.y), m1[0]);
        m1[1] = __builtin_elementwise_fma(f2, mkv(q0.z, q0.w), m1[1]);
        m1[2] = __builtin_elementwise_fma(f2, mkv(q1.x, q1.y), m1[2]);
        m1[3] = __builtin_elementwise_fma(f2, mkv(q1.z, q1.w), m1[3]);
        m1[4] = __builtin_elementwise_fma(f2, mkv(q2.x, q2.y), m1[4]);
        m1[5] = __builtin_elementwise_fma(f2, mkv(q2.z, q2.w), m1[5]);
        m1[6] = __builtin_elementwise_fma(f2, mkv(q3.x, q3.y), m1[6]);
        m1[7] = __builtin_elementwise_fma(f2, mkv(q3.z, q3.w), m1[7]);
    }
    v2f h[8];
    {
        const v2f* b1p = (const v2f*)&wS[B1O];
        const v2f k01 = mkv(0.01f, 0.01f);
#pragma unroll
        for (int p = 0; p < 8; ++p) {
            const v2f t = m1[p] + b1p[p];
            h[p] = __builtin_elementwise_max(t, t * k01);   // leaky
        }
    }

    // ---- g2 row: g2[n] = dot(h, w2[:,n]), packed over n ----
    v2f g22[4];
#pragma unroll
    for (int p = 0; p < 4; ++p) g22[p] = mkv(0.f, 0.f);
#pragma unroll
    for (int j = 0; j < 16; ++j) {
        const float hv = (j & 1) ? h[j >> 1].y : h[j >> 1].x;
        const v2f f2 = mkv(hv, hv);
        const float4* w2r = (const float4*)&wS[W2O + j * 8];
        const float4 r0 = w2r[0], r1 = w2r[1];
        g22[0] = __builtin_elementwise_fma(f2, mkv(r0.x, r0.y), g22[0]);
        g22[1] = __builtin_elementwise_fma(f2, mkv(r0.z, r0.w), g22[1]);
        g22[2] = __builtin_elementwise_fma(f2, mkv(r1.x, r1.y), g22[2]);
        g22[3] = __builtin_elementwise_fma(f2, mkv(r1.z, r1.w), g22[3]);
    }
    wavefence();   // S reads done -> overwrite A with g2
    {
        float4* gp = (float4*)(A + v * 8);
        gp[0] = make_float4(g22[0].x, g22[0].y, g22[1].x, g22[1].y);
        gp[1] = make_float4(g22[2].x, g22[2].y, g22[3].x, g22[3].y);
    }
    wavefence();

    // ---- layer 2: h2 = leaky(W @ g2 + b2), packed ----
    v2f m2[4];
#pragma unroll
    for (int p = 0; p < 4; ++p) m2[p] = mkv(0.f, 0.f);
#pragma unroll
    for (int w = 0; w < 8; ++w) {
        const float wv = (w & 1) ? W2[w >> 1].y : W2[w >> 1].x;
        const v2f f2 = mkv(wv, wv);
        const float4* gp = (const float4*)(A + w * 8);
        const float4 q0 = gp[0], q1 = gp[1];
        m2[0] = __builtin_elementwise_fma(f2, mkv(q0.x, q0.y), m2[0]);
        m2[1] = __builtin_elementwise_fma(f2, mkv(q0.z, q0.w), m2[1]);
        m2[2] = __builtin_elementwise_fma(f2, mkv(q1.x, q1.y), m2[2]);
        m2[3] = __builtin_elementwise_fma(f2, mkv(q1.z, q1.w), m2[3]);
    }
    v2f h2[4];
    {
        const v2f* b2p = (const v2f*)&wS[B2O];
        const v2f k01 = mkv(0.01f, 0.01f);
#pragma unroll
        for (int p = 0; p < 4; ++p) {
            const v2f t = m2[p] + b2p[p];
            h2[p] = __builtin_elementwise_max(t, t * k01);
        }
    }

    // ---- gate-logit row: Y[o] = dot(h2, wg[o,:]), packed over o via wgT ----
    v2f Y2[4];
#pragma unroll
    for (int p = 0; p < 4; ++p) Y2[p] = mkv(0.f, 0.f);
#pragma unroll
    for (int n = 0; n < 8; ++n) {
        const float hv = (n & 1) ? h2[n >> 1].y : h2[n >> 1].x;
        const v2f f2 = mkv(hv, hv);
        const float4* wgr = (const float4*)&wS[WGT + n * 8];
        const float4 r0 = wgr[0], r1 = wgr[1];
        Y2[0] = __builtin_elementwise_fma(f2, mkv(r0.x, r0.y), Y2[0]);
        Y2[1] = __builtin_elementwise_fma(f2, mkv(r0.z, r0.w), Y2[1]);
        Y2[2] = __builtin_elementwise_fma(f2, mkv(r1.x, r1.y), Y2[2]);
        Y2[3] = __builtin_elementwise_fma(f2, mkv(r1.z, r1.w), Y2[3]);
    }
    wavefence();   // g2 reads done; g1 (Bg) dead -> overwrite with h2 / Y / type
    {
        float4* hp = (float4*)(A + v * 8);
        hp[0] = make_float4(h2[0].x, h2[0].y, h2[1].x, h2[1].y);
        hp[1] = make_float4(h2[2].x, h2[2].y, h2[3].x, h2[3].y);
        float4* yp = (float4*)(Bg + v * 8);
        yp[0] = make_float4(Y2[0].x, Y2[0].y, Y2[1].x, Y2[1].y);
        yp[1] = make_float4(Y2[2].x, Y2[2].y, Y2[3].x, Y2[3].y);
        Bg[64 + v] = type;
    }
    wavefence();

    // ---- attention pooling: thread handles gate-row o = v.
    // bg[o] constant along softmax axis -> drops out; masked rows logit 0.
    const int o = v;
    float yc[8], hc[8], ty[8];
#pragma unroll
    for (int vp = 0; vp < 8; ++vp) {
        yc[vp] = Bg[vp * 8 + o];
        hc[vp] = A[vp * 8 + o];
        ty[vp] = Bg[64 + vp];
    }
    float xp = 0.f;
#pragma unroll
    for (int t = 0; t < 2; ++t) {
        const float tv = (float)t;
        float l[8];
        float lmx = -1e30f;
#pragma unroll
        for (int vp = 0; vp < 8; ++vp) {
            l[vp] = (ty[vp] == tv) ? yc[vp] : 0.f;
            lmx = fmaxf(lmx, l[vp]);
        }
        float esum = 0.f, num = 0.f;
#pragma unroll
        for (int vp = 0; vp < 8; ++vp) {
            const float e = __expf(l[vp] - lmx);
            esum += e;
            num  += (ty[vp] == tv) ? e * hc[vp] : 0.f;
        }
        xp += 0.5f * num / esum;
    }

    // ---- classifier ----
    const float y0 = grp_sum8(xp * wf[0 * 8 + o]);
    const float y1 = grp_sum8(xp * wf[1 * 8 + o]);
    if (v == 0) {
        float2* op = (float2*)(out + b * 2);
        *op = make_float2(y0 + bf[0], y1 + bf[1]);
    }
}

extern "C" void kernel_launch(void* const* d_in, const int* in_sizes, int n_in,
                              void* d_out, int out_size, void* d_ws, size_t ws_size,
                              hipStream_t stream) {
    const float* x    = (const float*)d_in[0];
    const float* adj  = (const float*)d_in[1];
    const float* edge = (const float*)d_in[2];
    // d_in[3]=wa, d_in[4]=ba unused by the reference.
    const float* wb   = (const float*)d_in[5];
    const float* bb   = (const float*)d_in[6];
    const float* w1   = (const float*)d_in[7];
    const float* b1   = (const float*)d_in[8];
    const float* w2   = (const float*)d_in[9];
    const float* b2   = (const float*)d_in[10];
    const float* wg   = (const float*)d_in[11];
    const float* bg   = (const float*)d_in[12];
    const float* wf   = (const float*)d_in[13];
    const float* bf   = (const float*)d_in[14];
    float* out = (float*)d_out;

    const int Btot    = in_sizes[0] / 264;            // B = 131072
    const int nGroups = (Btot + SLOTS - 1) / SLOTS;   // 8192

    gcn_fused<<<nGroups, NTHREADS, 0, stream>>>(x, adj, edge, wb, bb, w1, b1,
                                                w2, b2, wg, bg, wf, bf, out, nGroups);
}

// Round 7
// 269.246 us; speedup vs baseline: 2.2107x; 1.0242x over previous
//
#include <hip/hip_runtime.h>

// GCN_84499186582104 — fully fused, one thread per (batch, node).
// B=131072, V=8, NFEAT=32, NHID1=16, NHID12=8, NCLASS=2.
// R7 (base = R6, 92.5us):
//   - Coalesced x load: lane (slot,v) loads feature-chunk v of all 8 nodes
//     (8 coalesced float4, ~9 lines/instr vs ~60 for the old per-row loads),
//     stages into per-wave LDS with a (c+n+sl)&7 chunk swizzle (minimal
//     8-deep b128 bank schedule), reads back its own node row. Intra-wave
//     only -> wavefence, no __syncthreads.
//   - x-stage region aliases the A/B exchange buffers PER WAVE (no
//     cross-wave overlap): LDS = 20352 B -> 8 blocks/CU (50% cap).
//   - adj/edge/type issued at kernel top: 13 loads in flight.
//   - q[8] register array eliminated; VGPR stays < 64 (R3/R5 lesson).

#define SLOTS 16      // batches per block
#define NTHREADS 128  // 8 threads per batch; slots never span a wave

typedef float v2f __attribute__((ext_vector_type(2)));
typedef float4 __attribute__((aligned(4))) f4u;   // dword-aligned float4 load

// LDS float layout:
//   [0,4096): two wave regions of 2048 floats each; wavebase=(slot>>3)*2048
//     xstage: wavebase + sl*256 + n*32 + ((c+n+sl)&7)*4     (sl = slot&7)
//     A:      wavebase + sl*72            (aliases xstage after x reads)
//     B:      wavebase + 576 + sl*136
//   [4096,4096+992): weights
#define WBT 0     // wbT[c*8+o]                    (256)
#define W1O 256   // w1[c*16+j] natural            (512)
#define W2O 768   // w2[j*8+n]  natural            (128)
#define WGT 896   // wgT[n*8+o]                    (64)
#define BBO 960   // bb (8)
#define B1O 968   // b1 (16)
#define B2O 984   // b2 (8)
#define NWF 992

__device__ __forceinline__ float grp_sum8(float x) {
    x += __shfl_xor(x, 1);
    x += __shfl_xor(x, 2);
    x += __shfl_xor(x, 4);
    return x;
}
__device__ __forceinline__ void wavefence() { __builtin_amdgcn_wave_barrier(); }
__device__ __forceinline__ v2f mkv(float a, float b) { v2f r; r.x = a; r.y = b; return r; }

__global__ __launch_bounds__(NTHREADS, 4)
void gcn_fused(const float* __restrict__ x,
               const float* __restrict__ adj,
               const float* __restrict__ edge,
               const float* __restrict__ wb, const float* __restrict__ bb,
               const float* __restrict__ w1, const float* __restrict__ b1,
               const float* __restrict__ w2, const float* __restrict__ b2,
               const float* __restrict__ wg, const float* __restrict__ bg,
               const float* __restrict__ wf, const float* __restrict__ bf,
               float* __restrict__ out, int nGroups)
{
    __shared__ float lds[4096 + NWF];   // 20352 B

    const int tid  = threadIdx.x;
    const int slot = tid >> 3;
    const int v    = tid & 7;
    const int sl   = slot & 7;
    const int wavebase = (slot >> 3) * 2048;
    float* xW = &lds[wavebase + sl * 256];
    float* A  = &lds[wavebase + sl * 72];
    float* Bg = &lds[wavebase + 576 + sl * 136];
    float* wS = &lds[4096];

    // ---- stage weights into LDS (once per block; reads coalesced) ----
    for (int i = tid; i < 256; i += NTHREADS) {           // wb -> transposed
        const int o = i >> 5, c = i & 31;
        wS[WBT + c * 8 + o] = wb[i];
    }
    for (int i = tid; i < 512; i += NTHREADS) wS[W1O + i] = w1[i];
    if (tid < 128) wS[W2O + tid] = w2[tid];
    if (tid < 64) {                                        // wg -> transposed
        const int o = tid >> 3, n = tid & 7;
        wS[WGT + n * 8 + o] = wg[tid];
    }
    if (tid < 8)  wS[BBO + tid] = bb[tid];
    if (tid < 16) wS[B1O + tid] = b1[tid];
    if (tid < 8)  wS[B2O + tid] = b2[tid];
    __syncthreads();

    long long bb_ = (long long)blockIdx.x * SLOTS + slot;
    if (bb_ >= (long long)nGroups * SLOTS) bb_ = (long long)nGroups * SLOTS - 1;
    const size_t b = (size_t)bb_;

    // ---- all global loads issued up front (max MLP) ----
    const float4* ar = (const float4*)(adj  + b * 64 + (size_t)v * 8);
    const float4* er = (const float4*)(edge + b * 64 + (size_t)v * 8);
    const float4 a0 = ar[0], a1 = ar[1];
    const float4 e0 = er[0], e1 = er[1];

    const float* xb = x + b * 264;
    const float type = xb[v * 33];                 // own node's type
    float4 xf[8];                                  // chunk v of each node n
#pragma unroll
    for (int n = 0; n < 8; ++n)
        xf[n] = *(const f4u*)(xb + n * 33 + 1 + v * 4);

    // ---- stage x into LDS (swizzled), read back own row ----
#pragma unroll
    for (int n = 0; n < 8; ++n)
        *(float4*)(xW + n * 32 + (((v + n + sl) & 7) << 2)) = xf[n];
    wavefence();

    const int K0 = (v + sl) & 7;

    // ---- Fk (output-paired) + g1 (output-paired), packed fp32 ----
    v2f Fk2[4];
    {
        const v2f* bbp = (const v2f*)&wS[BBO];
#pragma unroll
        for (int p = 0; p < 4; ++p) Fk2[p] = bbp[p];
    }
    v2f g12[8];
#pragma unroll
    for (int p = 0; p < 8; ++p) g12[p] = mkv(0.f, 0.f);
#pragma unroll
    for (int k = 0; k < 8; ++k) {
        const float4 qk = *(const float4*)(xW + v * 32 + (((k + K0) & 7) << 2));
        const float f[4] = { qk.x, qk.y, qk.z, qk.w };
#pragma unroll
        for (int u = 0; u < 4; ++u) {
            const int c = 4 * k + u;
            const v2f f2 = mkv(f[u], f[u]);
            const float4* wbc = (const float4*)&wS[WBT + c * 8];
            const float4 wa = wbc[0], wbq = wbc[1];
            Fk2[0] = __builtin_elementwise_fma(f2, mkv(wa.x,  wa.y),  Fk2[0]);
            Fk2[1] = __builtin_elementwise_fma(f2, mkv(wa.z,  wa.w),  Fk2[1]);
            Fk2[2] = __builtin_elementwise_fma(f2, mkv(wbq.x, wbq.y), Fk2[2]);
            Fk2[3] = __builtin_elementwise_fma(f2, mkv(wbq.z, wbq.w), Fk2[3]);
            const float4* w1c = (const float4*)&wS[W1O + c * 16];
            const float4 wc0 = w1c[0], wc1 = w1c[1], wc2 = w1c[2], wc3 = w1c[3];
            g12[0] = __builtin_elementwise_fma(f2, mkv(wc0.x, wc0.y), g12[0]);
            g12[1] = __builtin_elementwise_fma(f2, mkv(wc0.z, wc0.w), g12[1]);
            g12[2] = __builtin_elementwise_fma(f2, mkv(wc1.x, wc1.y), g12[2]);
            g12[3] = __builtin_elementwise_fma(f2, mkv(wc1.z, wc1.w), g12[3]);
            g12[4] = __builtin_elementwise_fma(f2, mkv(wc2.x, wc2.y), g12[4]);
            g12[5] = __builtin_elementwise_fma(f2, mkv(wc2.z, wc2.w), g12[5]);
            g12[6] = __builtin_elementwise_fma(f2, mkv(wc3.x, wc3.y), g12[6]);
            g12[7] = __builtin_elementwise_fma(f2, mkv(wc3.z, wc3.w), g12[7]);
        }
    }
    wavefence();   // all xW reads done -> A/B may overwrite (same wave region)

    // ---- share Fk (column v) and g1 (row v) ----
#pragma unroll
    for (int p = 0; p < 4; ++p) {
        A[(2 * p)     * 8 + v] = Fk2[p].x;
        A[(2 * p + 1) * 8 + v] = Fk2[p].y;
    }
    {
        float4* gp = (float4*)(Bg + v * 16);
        gp[0] = make_float4(g12[0].x, g12[0].y, g12[1].x, g12[1].y);
        gp[1] = make_float4(g12[2].x, g12[2].y, g12[3].x, g12[3].y);
        gp[2] = make_float4(g12[4].x, g12[4].y, g12[5].x, g12[5].y);
        gp[3] = make_float4(g12[6].x, g12[6].y, g12[7].x, g12[7].y);
    }
    wavefence();

    // ---- M[o][v] = dot(FkS row o, Fk column v); softmax over o ----
    float M[8];
#pragma unroll
    for (int o = 0; o < 8; ++o) {
        const float4* fr = (const float4*)(A + o * 8);
        const float4 r0 = fr[0], r1 = fr[1];
        v2f acc = mkv(0.f, 0.f);
        acc = __builtin_elementwise_fma(mkv(r0.x, r0.y), Fk2[0], acc);
        acc = __builtin_elementwise_fma(mkv(r0.z, r0.w), Fk2[1], acc);
        acc = __builtin_elementwise_fma(mkv(r1.x, r1.y), Fk2[2], acc);
        acc = __builtin_elementwise_fma(mkv(r1.z, r1.w), Fk2[3], acc);
        M[o] = acc.x + acc.y;
    }
    wavefence();
    float mx = M[0];
#pragma unroll
    for (int o = 1; o < 8; ++o) mx = fmaxf(mx, M[o]);
    float ssum = 0.f;
#pragma unroll
    for (int o = 0; o < 8; ++o) { M[o] = __expf(M[o] - mx); ssum += M[o]; }
    const float sinv = 1.f / ssum;
#pragma unroll
    for (int o = 0; o < 8; ++o) A[o * 8 + v] = M[o] * sinv;   // S column
    wavefence();

    // ---- W row (packed): W = adj * (S + edge) ----
    const float4* sr = (const float4*)(A + v * 8);
    const float4 s0 = sr[0], s1 = sr[1];
    v2f W2[4];
    W2[0] = mkv(a0.x, a0.y) * (mkv(s0.x, s0.y) + mkv(e0.x, e0.y));
    W2[1] = mkv(a0.z, a0.w) * (mkv(s0.z, s0.w) + mkv(e0.z, e0.w));
    W2[2] = mkv(a1.x, a1.y) * (mkv(s1.x, s1.y) + mkv(e1.x, e1.y));
    W2[3] = mkv(a1.z, a1.w) * (mkv(s1.z, s1.w) + mkv(e1.z, e1.w));

    // ---- layer 1: h = leaky(W @ g1 + b1), packed ----
    v2f m1[8];
#pragma unroll
    for (int p = 0; p < 8; ++p) m1[p] = mkv(0.f, 0.f);
#pragma unroll
    for (int w = 0; w < 8; ++w) {
        const float wv = (w & 1) ? W2[w >> 1].y : W2[w >> 1].x;
        const v2f f2 = mkv(wv, wv);
        const float4* gp = (const float4*)(Bg + w * 16);
        const float4 q0 = gp[0], q1 = gp[1], q2 = gp[2], q3 = gp[3];
        m1[0] = __builtin_elementwise_fma(f2, mkv(q0.x, q0.y), m1[0]);
        m1[1] = __builtin_elementwise_fma(f2, mkv(q0.z, q0.w), m1[1]);
        m1[2] = __builtin_elementwise_fma(f2, mkv(q1.x, q1.y), m1[2]);
        m1[3] = __builtin_elementwise_fma(f2, mkv(q1.z, q1.w), m1[3]);
        m1[4] = __builtin_elementwise_fma(f2, mkv(q2.x, q2.y), m1[4]);
        m1[5] = __builtin_elementwise_fma(f2, mkv(q2.z, q2.w), m1[5]);
        m1[6] = __builtin_elementwise_fma(f2, mkv(q3.x, q3.y), m1[6]);
        m1[7] = __builtin_elementwise_fma(f2, mkv(q3.z, q3.w), m1[7]);
    }
    v2f h[8];
    {
        const v2f* b1p = (const v2f*)&wS[B1O];
        const v2f k01 = mkv(0.01f, 0.01f);
#pragma unroll
        for (int p = 0; p < 8; ++p) {
            const v2f t = m1[p] + b1p[p];
            h[p] = __builtin_elementwise_max(t, t * k01);   // leaky
        }
    }

    // ---- g2 row: g2[n] = dot(h, w2[:,n]), packed over n ----
    v2f g22[4];
#pragma unroll
    for (int p = 0; p < 4; ++p) g22[p] = mkv(0.f, 0.f);
#pragma unroll
    for (int j = 0; j < 16; ++j) {
        const float hv = (j & 1) ? h[j >> 1].y : h[j >> 1].x;
        const v2f f2 = mkv(hv, hv);
        const float4* w2r = (const float4*)&wS[W2O + j * 8];
        const float4 r0 = w2r[0], r1 = w2r[1];
        g22[0] = __builtin_elementwise_fma(f2, mkv(r0.x, r0.y), g22[0]);
        g22[1] = __builtin_elementwise_fma(f2, mkv(r0.z, r0.w), g22[1]);
        g22[2] = __builtin_elementwise_fma(f2, mkv(r1.x, r1.y), g22[2]);
        g22[3] = __builtin_elementwise_fma(f2, mkv(r1.z, r1.w), g22[3]);
    }
    wavefence();   // S reads done -> overwrite A with g2
    {
        float4* gp = (float4*)(A + v * 8);
        gp[0] = make_float4(g22[0].x, g22[0].y, g22[1].x, g22[1].y);
        gp[1] = make_float4(g22[2].x, g22[2].y, g22[3].x, g22[3].y);
    }
    wavefence();

    // ---- layer 2: h2 = leaky(W @ g2 + b2), packed ----
    v2f m2[4];
#pragma unroll
    for (int p = 0; p < 4; ++p) m2[p] = mkv(0.f, 0.f);
#pragma unroll
    for (int w = 0; w < 8; ++w) {
        const float wv = (w & 1) ? W2[w >> 1].y : W2[w >> 1].x;
        const v2f f2 = mkv(wv, wv);
        const float4* gp = (const float4*)(A + w * 8);
        const float4 q0 = gp[0], q1 = gp[1];
        m2[0] = __builtin_elementwise_fma(f2, mkv(q0.x, q0.y), m2[0]);
        m2[1] = __builtin_elementwise_fma(f2, mkv(q0.z, q0.w), m2[1]);
        m2[2] = __builtin_elementwise_fma(f2, mkv(q1.x, q1.y), m2[2]);
        m2[3] = __builtin_elementwise_fma(f2, mkv(q1.z, q1.w), m2[3]);
    }
    v2f h2[4];
    {
        const v2f* b2p = (const v2f*)&wS[B2O];
        const v2f k01 = mkv(0.01f, 0.01f);
#pragma unroll
        for (int p = 0; p < 4; ++p) {
            const v2f t = m2[p] + b2p[p];
            h2[p] = __builtin_elementwise_max(t, t * k01);
        }
    }

    // ---- gate-logit row: Y[o] = dot(h2, wg[o,:]), packed over o via wgT ----
    v2f Y2[4];
#pragma unroll
    for (int p = 0; p < 4; ++p) Y2[p] = mkv(0.f, 0.f);
#pragma unroll
    for (int n = 0; n < 8; ++n) {
        const float hv = (n & 1) ? h2[n >> 1].y : h2[n >> 1].x;
        const v2f f2 = mkv(hv, hv);
        const float4* wgr = (const float4*)&wS[WGT + n * 8];
        const float4 r0 = wgr[0], r1 = wgr[1];
        Y2[0] = __builtin_elementwise_fma(f2, mkv(r0.x, r0.y), Y2[0]);
        Y2[1] = __builtin_elementwise_fma(f2, mkv(r0.z, r0.w), Y2[1]);
        Y2[2] = __builtin_elementwise_fma(f2, mkv(r1.x, r1.y), Y2[2]);
        Y2[3] = __builtin_elementwise_fma(f2, mkv(r1.z, r1.w), Y2[3]);
    }
    wavefence();   // g2 reads done; g1 (Bg) dead -> overwrite with h2 / Y / type
    {
        float4* hp = (float4*)(A + v * 8);
        hp[0] = make_float4(h2[0].x, h2[0].y, h2[1].x, h2[1].y);
        hp[1] = make_float4(h2[2].x, h2[2].y, h2[3].x, h2[3].y);
        float4* yp = (float4*)(Bg + v * 8);
        yp[0] = make_float4(Y2[0].x, Y2[0].y, Y2[1].x, Y2[1].y);
        yp[1] = make_float4(Y2[2].x, Y2[2].y, Y2[3].x, Y2[3].y);
        Bg[64 + v] = type;
    }
    wavefence();

    // ---- attention pooling: thread handles gate-row o = v.
    // bg[o] constant along softmax axis -> drops out; masked rows logit 0.
    const int o = v;
    float yc[8], hc[8], ty[8];
#pragma unroll
    for (int vp = 0; vp < 8; ++vp) {
        yc[vp] = Bg[vp * 8 + o];
        hc[vp] = A[vp * 8 + o];
        ty[vp] = Bg[64 + vp];
    }
    float xp = 0.f;
#pragma unroll
    for (int t = 0; t < 2; ++t) {
        const float tv = (float)t;
        float l[8];
        float lmx = -1e30f;
#pragma unroll
        for (int vp = 0; vp < 8; ++vp) {
            l[vp] = (ty[vp] == tv) ? yc[vp] : 0.f;
            lmx = fmaxf(lmx, l[vp]);
        }
        float esum = 0.f, num = 0.f;
#pragma unroll
        for (int vp = 0; vp < 8; ++vp) {
            const float e = __expf(l[vp] - lmx);
            esum += e;
            num  += (ty[vp] == tv) ? e * hc[vp] : 0.f;
        }
        xp += 0.5f * num / esum;
    }

    // ---- classifier ----
    const float y0 = grp_sum8(xp * wf[0 * 8 + o]);
    const float y1 = grp_sum8(xp * wf[1 * 8 + o]);
    if (v == 0) {
        float2* op = (float2*)(out + b * 2);
        *op = make_float2(y0 + bf[0], y1 + bf[1]);
    }
}

extern "C" void kernel_launch(void* const* d_in, const int* in_sizes, int n_in,
                              void* d_out, int out_size, void* d_ws, size_t ws_size,
                              hipStream_t stream) {
    const float* x    = (const float*)d_in[0];
    const float* adj  = (const float*)d_in[1];
    const float* edge = (const float*)d_in[2];
    // d_in[3]=wa, d_in[4]=ba unused by the reference.
    const float* wb   = (const float*)d_in[5];
    const float* bb   = (const float*)d_in[6];
    const float* w1   = (const float*)d_in[7];
    const float* b1   = (const float*)d_in[8];
    const float* w2   = (const float*)d_in[9];
    const float* b2   = (const float*)d_in[10];
    const float* wg   = (const float*)d_in[11];
    const float* bg   = (const float*)d_in[12];
    const float* wf   = (const float*)d_in[13];
    const float* bf   = (const float*)d_in[14];
    float* out = (float*)d_out;

    const int Btot    = in_sizes[0] / 264;            // B = 131072
    const int nGroups = (Btot + SLOTS - 1) / SLOTS;   // 8192

    gcn_fused<<<nGroups, NTHREADS, 0, stream>>>(x, adj, edge, wb, bb, w1, b1,
                                                w2, b2, wg, bg, wf, bf, out, nGroups);
}